// Round 1
// baseline (421.188 us; speedup 1.0000x reference)
//
#include <hip/hip_runtime.h>
#include <hip/hip_bf16.h>
#include <stdint.h>

#define NTOK 16384
#define DDIM 4096
#define NEXP 128
#define BM 64
#define BK 64
#define NT (DDIM / BK)   // 64 k-tiles

typedef __attribute__((ext_vector_type(8))) short short8;   // 8 bf16 = 4 VGPRs (MFMA A/B frag)
typedef __attribute__((ext_vector_type(4))) float f32x4;    // MFMA C/D frag
typedef __attribute__((address_space(1))) const uint32_t gu32;
typedef __attribute__((address_space(3))) uint32_t lu32;

// async global->LDS, 16B per lane. Dest must be wave-uniform base + lane*16 (linear).
__device__ __forceinline__ void gload16(const void* g, void* l) {
    __builtin_amdgcn_global_load_lds((gu32*)g, (lu32*)l, 16, 0, 0);
}

// fp32 -> (hi, lo) bf16 pair, both RNE. f ~= hi + lo with |err| <~ 2^-17 |f|.
__device__ __forceinline__ void split_bf16(float f, uint32_t& h, uint32_t& l) {
    uint32_t u = __float_as_uint(f);
    h = (u + 0x7FFFu + ((u >> 16) & 1u)) >> 16;
    float r = f - __uint_as_float(h << 16);
    uint32_t v = __float_as_uint(r);
    l = (v + 0x7FFFu + ((v >> 16) & 1u)) >> 16;
}

// ---- kernel 1: split wg_weight [128][4096] fp32 -> w_hi, w_lo bf16 in ws ----
__global__ void prep_w(const float* __restrict__ w,
                       uint16_t* __restrict__ whi, uint16_t* __restrict__ wlo) {
    int i = (blockIdx.x * blockDim.x + threadIdx.x) * 4;
    float4 f = *(const float4*)(w + i);
    uint32_t h0, h1, h2, h3, l0, l1, l2, l3;
    split_bf16(f.x, h0, l0);
    split_bf16(f.y, h1, l1);
    split_bf16(f.z, h2, l2);
    split_bf16(f.w, h3, l3);
    uint2 hv = make_uint2(h0 | (h1 << 16), h2 | (h3 << 16));
    uint2 lv = make_uint2(l0 | (l1 << 16), l2 | (l3 << 16));
    *(uint2*)(whi + i) = hv;
    *(uint2*)(wlo + i) = lv;
}

// ---- kernel 2: logits = x @ w^T via split-bf16 3-product MFMA ----
// BM=64 tokens x 128 experts per block, 512 threads = 8 waves (2 row x 4 col),
// each wave owns a 32x32 output tile. Double-buffered LDS, 1 barrier/iter.
// LDS layout: linear [rows][64] bf16 (128 B/row), XOR-swizzled 16B chunks:
//   LDS(r, j) holds global chunk (r, j ^ (r&7))  -- conflict-free ds_read_b128
//   and compatible with global_load_lds linear dest (source pre-swizzled).
__global__ __launch_bounds__(512, 1) void gemm_logits(
    const float* __restrict__ x,
    const uint16_t* __restrict__ whi, const uint16_t* __restrict__ wlo,
    float* __restrict__ S)
{
    __shared__ uint16_t sAh[2][BM * BK], sAl[2][BM * BK];     // 16 KB + 16 KB
    __shared__ uint16_t sBh[2][NEXP * BK], sBl[2][NEXP * BK]; // 32 KB + 32 KB  (96 KB total)

    const int tid  = threadIdx.x;
    const int lane = tid & 63;
    const int wave = tid >> 6;
    const int wr = wave >> 2;      // wave row (0..1): tokens
    const int wc = wave & 3;       // wave col (0..3): experts
    const int q = lane >> 4;       // quad id, k-group selector
    const int c = lane & 15;       // row (A) / col (B) within 16
    const int rxor = c & 7;        // all frag rows have row&7 == c&7
    const int m0 = blockIdx.x * BM;

    // A staging: thread t -> row ar = t>>3, 8-float chunk aj = t&7
    const int ar = tid >> 3, aj = tid & 7;
    const float* xp = x + (size_t)(m0 + ar) * DDIM + aj * 8;
    const int aoff = ar * BK + (aj ^ (ar & 7)) * 8;   // swizzled LDS elem offset

    // B staging: same (row, chunk) decomposition; source pre-swizzled so the
    // linear global_load_lds dest realizes the same XOR layout. Second chunk
    // is +64 rows (64 & 7 == 0 so the XOR is unchanged).
    const int bjj = aj ^ (ar & 7);
    const size_t bgo0 = (size_t)ar * DDIM + bjj * 8;
    const size_t bgo1 = bgo0 + (size_t)64 * DDIM;
    const int bd0 = tid * 8, bd1 = (tid + 512) * 8;

    f32x4 acc[2][2];
    #pragma unroll
    for (int mt = 0; mt < 2; ++mt)
        #pragma unroll
        for (int nt = 0; nt < 2; ++nt)
            acc[mt][nt] = (f32x4){0.f, 0.f, 0.f, 0.f};

    const int rA0 = (wr * 32 + c) * BK;
    const int rB0 = (wc * 32 + c) * BK;

    auto stageB = [&](int nxt, int kn) {
        gload16(whi + bgo0 + kn, &sBh[nxt][bd0]);
        gload16(whi + bgo1 + kn, &sBh[nxt][bd1]);
        gload16(wlo + bgo0 + kn, &sBl[nxt][bd0]);
        gload16(wlo + bgo1 + kn, &sBl[nxt][bd1]);
    };

    auto writeA = [&](int nxt, float4 fa, float4 fb) {
        uint32_t h[8], l[8];
        split_bf16(fa.x, h[0], l[0]); split_bf16(fa.y, h[1], l[1]);
        split_bf16(fa.z, h[2], l[2]); split_bf16(fa.w, h[3], l[3]);
        split_bf16(fb.x, h[4], l[4]); split_bf16(fb.y, h[5], l[5]);
        split_bf16(fb.z, h[6], l[6]); split_bf16(fb.w, h[7], l[7]);
        uint4 hv = make_uint4(h[0] | (h[1] << 16), h[2] | (h[3] << 16),
                              h[4] | (h[5] << 16), h[6] | (h[7] << 16));
        uint4 lv = make_uint4(l[0] | (l[1] << 16), l[2] | (l[3] << 16),
                              l[4] | (l[5] << 16), l[6] | (l[7] << 16));
        *(uint4*)&sAh[nxt][aoff] = hv;
        *(uint4*)&sAl[nxt][aoff] = lv;
    };

    auto compute = [&](int cur) {
        #pragma unroll
        for (int ks = 0; ks < 2; ++ks) {
            const int off = ((((ks << 2) | q)) ^ rxor) << 3;  // swizzled chunk
            short8 ah[2], alo[2], bh[2], blo[2];
            #pragma unroll
            for (int mt = 0; mt < 2; ++mt) {
                const int ro = rA0 + mt * 16 * BK + off;
                ah[mt]  = *(const short8*)&sAh[cur][ro];
                alo[mt] = *(const short8*)&sAl[cur][ro];
            }
            #pragma unroll
            for (int nt = 0; nt < 2; ++nt) {
                const int ro = rB0 + nt * 16 * BK + off;
                bh[nt]  = *(const short8*)&sBh[cur][ro];
                blo[nt] = *(const short8*)&sBl[cur][ro];
            }
            #pragma unroll
            for (int mt = 0; mt < 2; ++mt)
                #pragma unroll
                for (int nt = 0; nt < 2; ++nt) {
                    acc[mt][nt] = __builtin_amdgcn_mfma_f32_16x16x32_bf16(alo[mt], bh[nt],  acc[mt][nt], 0, 0, 0);
                    acc[mt][nt] = __builtin_amdgcn_mfma_f32_16x16x32_bf16(ah[mt],  blo[nt], acc[mt][nt], 0, 0, 0);
                    acc[mt][nt] = __builtin_amdgcn_mfma_f32_16x16x32_bf16(ah[mt],  bh[nt],  acc[mt][nt], 0, 0, 0);
                }
        }
    };

    // ---- prologue: stage tile 0 into buf 0 ----
    stageB(0, 0);
    {
        float4 fa = *(const float4*)(xp);
        float4 fb = *(const float4*)(xp + 4);
        writeA(0, fa, fb);
    }
    __syncthreads();   // compiler emits vmcnt(0) lgkmcnt(0) drain -> gload_lds landed

    // ---- main loop: issue next-tile loads early, compute current, write-late ----
    #pragma unroll 2
    for (int t = 0; t < NT - 1; ++t) {
        const int cur = t & 1, nxt = cur ^ 1;
        const int kn = (t + 1) * BK;
        stageB(nxt, kn);                            // async B -> LDS (lands under compute)
        float4 fa = *(const float4*)(xp + kn);      // async A -> regs
        float4 fb = *(const float4*)(xp + kn + 4);
        compute(cur);
        writeA(nxt, fa, fb);                        // split + ds_write after MFMAs
        __syncthreads();
    }
    compute((NT - 1) & 1);

    // ---- epilogue: C/D layout col=lane&15, row=(lane>>4)*4+reg (m89-verified) ----
    #pragma unroll
    for (int mt = 0; mt < 2; ++mt)
        #pragma unroll
        for (int nt = 0; nt < 2; ++nt) {
            const int e = wc * 32 + nt * 16 + c;
            #pragma unroll
            for (int r = 0; r < 4; ++r) {
                const int tok = m0 + wr * 32 + mt * 16 + q * 4 + r;
                S[(size_t)tok * NEXP + e] = acc[mt][nt][r];
            }
        }
}

// ---- kernel 3: masked softmax + adaptive top-k, one wave per token ----
__global__ __launch_bounds__(256) void postproc(
    float* __restrict__ S, const float* __restrict__ mask,
    float* __restrict__ topk_out)
{
    const int lane = threadIdx.x & 63;
    const int wave = threadIdx.x >> 6;
    const int t = blockIdx.x * 4 + wave;
    float* row = S + (size_t)t * NEXP;

    float s0 = row[lane], s1 = row[lane + 64];
    float mk0 = mask[lane], mk1 = mask[lane + 64];
    const bool a0 = (mk0 != 0.f), a1 = (mk1 != 0.f);

    // max over active logits
    float mx = fmaxf(a0 ? s0 : -3.0e38f, a1 ? s1 : -3.0e38f);
    #pragma unroll
    for (int off = 32; off; off >>= 1) mx = fmaxf(mx, __shfl_xor(mx, off));

    float p0 = a0 ? __expf(s0 - mx) : 0.f;
    float p1 = a1 ? __expf(s1 - mx) : 0.f;
    float sum = p0 + p1;
    #pragma unroll
    for (int off = 32; off; off >>= 1) sum += __shfl_xor(sum, off);

    const float inv = 1.0f / sum;
    const float sc0 = p0 * inv + 1e-14f;
    const float sc1 = p1 * inv + 1e-14f;
    row[lane]      = sc0;
    row[lane + 64] = sc1;

    const int active = __popcll(__ballot(a0)) + __popcll(__ballot(a1));

    // adaptive top-k: extract maxima until cumulative mass >= 0.5.
    float v0 = sc0, v1 = sc1;
    float cum = 0.f;
    int k = 0;
    while (cum < 0.5f && k < NEXP) {
        float mv = fmaxf(v0, v1);
        #pragma unroll
        for (int off = 32; off; off >>= 1) mv = fmaxf(mv, __shfl_xor(mv, off));
        cum += mv;
        ++k;
        unsigned long long b = __ballot(v0 == mv || v1 == mv);
        int first = __ffsll(b) - 1;
        if (lane == first) {
            if (v0 == mv) v0 = -1.f; else v1 = -1.f;
        }
    }
    int topk = k < active ? k : active;
    if (lane == 0) topk_out[t] = (float)topk;
}

extern "C" void kernel_launch(void* const* d_in, const int* in_sizes, int n_in,
                              void* d_out, int out_size, void* d_ws, size_t ws_size,
                              hipStream_t stream) {
    (void)in_sizes; (void)n_in; (void)out_size; (void)ws_size;
    const float* x    = (const float*)d_in[0];
    const float* w    = (const float*)d_in[1];
    const float* mask = (const float*)d_in[2];

    float* S    = (float*)d_out;                  // [16384,128] scores (also logit scratch)
    float* topk = S + (size_t)NTOK * NEXP;        // [16384] top_k as float

    uint16_t* whi = (uint16_t*)d_ws;              // [128,4096] bf16 hi
    uint16_t* wlo = whi + (size_t)NEXP * DDIM;    // [128,4096] bf16 lo

    hipLaunchKernelGGL(prep_w, dim3((NEXP * DDIM) / (256 * 4)), dim3(256), 0, stream,
                       w, whi, wlo);
    hipLaunchKernelGGL(gemm_logits, dim3(NTOK / BM), dim3(512), 0, stream,
                       x, whi, wlo, S);
    hipLaunchKernelGGL(postproc, dim3(NTOK / 4), dim3(256), 0, stream,
                       S, mask, topk);
}